// Round 20
// baseline (153.037 us; speedup 1.0000x reference)
//
#include <hip/hip_runtime.h>
#include <stdint.h>
#include <stddef.h>

typedef __attribute__((ext_vector_type(4))) int i32x4;

#define AS1q __attribute__((address_space(1)))
#define AS3q __attribute__((address_space(3)))

__device__ __forceinline__ void gload16(const void* g, void* l) {
    __builtin_amdgcn_global_load_lds((const AS1q uint32_t*)g, (AS3q uint32_t*)l, 16, 0, 0);
}

#define VMCNT0()  asm volatile("s_waitcnt vmcnt(0)" ::: "memory")
#define BARRIER() asm volatile("s_barrier" ::: "memory")
#define SB()      __builtin_amdgcn_sched_barrier(0)
#define SP1()     __builtin_amdgcn_s_setprio(1)
#define SP0()     __builtin_amdgcn_s_setprio(0)
#define MFMAI8(a, b, c) __builtin_amdgcn_mfma_i32_16x16x64_i8(a, b, c, 0, 0, 0)

#define EPSQ 1e-8f

// ---------------- Quant: one block per token (K == 4096 fast path) ----------------
__global__ __launch_bounds__(256) void quant4096(
    const float* __restrict__ x, int8_t* __restrict__ xq, float* __restrict__ sx)
{
    constexpr int K = 4096;
    const int t = blockIdx.x;
    const int tid = threadIdx.x;
    const float4* row4 = (const float4*)(x + (size_t)t * K);
    float4 v0 = row4[0 * 256 + tid];
    float4 v1 = row4[1 * 256 + tid];
    float4 v2 = row4[2 * 256 + tid];
    float4 v3 = row4[3 * 256 + tid];
    auto mx4 = [](float4 a) {
        return fmaxf(fmaxf(fabsf(a.x), fabsf(a.y)), fmaxf(fabsf(a.z), fabsf(a.w)));
    };
    float am = fmaxf(fmaxf(mx4(v0), mx4(v1)), fmaxf(mx4(v2), mx4(v3)));
    #pragma unroll
    for (int off = 32; off > 0; off >>= 1)
        am = fmaxf(am, __shfl_xor(am, off, 64));
    __shared__ float wmax[4];
    if ((tid & 63) == 0) wmax[tid >> 6] = am;
    __syncthreads();
    float r = fmaxf(fmaxf(wmax[0], wmax[1]), fmaxf(wmax[2], wmax[3]));
    const float s = fmaxf(r, EPSQ) / 127.0f;   // true fdiv: match reference
    if (tid == 0) sx[t] = s;
    int* qrow = (int*)(xq + (size_t)t * K);
    auto pack = [&](float4 a) {
        int q0 = (int)fminf(fmaxf(rintf(a.x / s), -128.f), 127.f);
        int q1 = (int)fminf(fmaxf(rintf(a.y / s), -128.f), 127.f);
        int q2 = (int)fminf(fmaxf(rintf(a.z / s), -128.f), 127.f);
        int q3 = (int)fminf(fmaxf(rintf(a.w / s), -128.f), 127.f);
        return (q0 & 255) | ((q1 & 255) << 8) | ((q2 & 255) << 16) | ((q3 & 255) << 24);
    };
    qrow[0 * 256 + tid] = pack(v0);
    qrow[1 * 256 + tid] = pack(v1);
    qrow[2 * 256 + tid] = pack(v2);
    qrow[3 * 256 + tid] = pack(v3);
}

// generic fallback (any K multiple of 4)
__global__ __launch_bounds__(256) void quant_any(
    const float* __restrict__ x, int8_t* __restrict__ xq, float* __restrict__ sx, int K)
{
    const int t = blockIdx.x;
    const int tid = threadIdx.x;
    const float* row = x + (size_t)t * K;
    float am = 0.f;
    for (int i = tid; i < K; i += 256) am = fmaxf(am, fabsf(row[i]));
    #pragma unroll
    for (int off = 32; off > 0; off >>= 1)
        am = fmaxf(am, __shfl_xor(am, off, 64));
    __shared__ float wmax[4];
    if ((tid & 63) == 0) wmax[tid >> 6] = am;
    __syncthreads();
    float r = fmaxf(fmaxf(wmax[0], wmax[1]), fmaxf(wmax[2], wmax[3]));
    const float s = fmaxf(r, EPSQ) / 127.0f;
    if (tid == 0) sx[t] = s;
    int8_t* qrow = xq + (size_t)t * K;
    for (int i = tid; i < K; i += 256) {
        float q = fminf(fmaxf(rintf(row[i] / s), -128.f), 127.f);
        qrow[i] = (int8_t)(int)q;
    }
}

// ---------------- Pack: weight arrives as int32 (harness ABI), repack to int8 ----------------
__global__ __launch_bounds__(256) void pack_w(
    const int* __restrict__ w32, int8_t* __restrict__ w8, long long n4)
{
    const long long stride = (long long)gridDim.x * 256;
    for (long long i = (long long)blockIdx.x * 256 + threadIdx.x; i < n4; i += stride) {
        int4 v = ((const int4*)w32)[i];
        ((int*)w8)[i] = (v.x & 255) | ((v.y & 255) << 8) | ((v.z & 255) << 16) | ((v.w & 255) << 24);
    }
}

// ---------------- int8 GEMM: R19 body at BK=64, 2 blocks/CU (4 waves/SIMD) ----------------
// BM=256, BN=192, BK=64. 512 thr, 8 waves (4M x 2N), wave tile 64x96 = 4x6
// frags 16x16x64 -> 24 MFMA + 10 ds_read_b128 per wave per K-tile.
// CHANGE vs R19 (neutral LDS-traffic cut proved LDS BW non-binding; limiter
// is intra-wave serialization at 2 waves/SIMD): halve BK -> LDS 2 bufs x 28KB
// = 56KB -> TWO co-resident 512-thr blocks/CU = 4 waves/SIMD. Two INDEPENDENT
// barrier groups stagger (m114; R6->R7's +15% was exactly this mechanism):
// block A's MFMA clusters fill block B's read/drain gaps. Grid 512 = all
// blocks resident simultaneously, zero tail. VGPR must stay <=128 (R19: 112).
// Schedule per tile: R12/R19's straight-line sched_barrier(0) walls, ONE
// vmcnt(0)+barrier per tile (counted vmcnt measured -22/-35%), stage mid-body.
// Swizzle: R2-counter-verified two-64B-rows-per-128B-phys XOR x^=(R&7)<<4;
// linear gload_lds dest + inverse-swizzled per-lane global src (rule #21).
// B region = 12KB = 768 chunks: 512 thr do one load, tid<256 (waves 0-3,
// wave-uniform branch) do a second. Per-wave vmcnt0 drains its own loads.
__global__ __launch_bounds__(512, 2) void gemm_i8(
    const int8_t* __restrict__ xq, const int8_t* __restrict__ w,
    const float* __restrict__ sx, const float* __restrict__ scale,
    const float* __restrict__ bias, float* __restrict__ out,
    int M, int N, int K)
{
    __shared__ __align__(16) uint8_t lds[2][28672];   // [buf][A 16KB | B 12KB] = 56KB
    const int tid  = threadIdx.x;
    const int lane = tid & 63;
    const int wv   = tid >> 6;
    const int wr   = wv >> 1, wc = wv & 1;           // 4M x 2N

    // bijective XCD swizzle (m204); nwg=512 -> %8==0
    const int nwg = gridDim.x;
    const int q8 = nwg >> 3, r8 = nwg & 7;
    const int xcd = blockIdx.x & 7, idx8 = blockIdx.x >> 3;
    const int wg = (xcd < r8 ? xcd * (q8 + 1) : r8 * (q8 + 1) + (xcd - r8) * q8) + idx8;

    const int NBM = M >> 8;
    const int bm = wg % NBM;
    const int bn = wg / NBM;             // col-panel-major: B panel (768KB) L2-resident
    const int brow = bm << 8, bcol = bn * 192;

    // staging sources (inverse-swizzled; R2-verified formula).
    // A region 16KB = 1024 chunks: li = e*512 + tid, e in {0,1}.
    const int8_t* srcA[2];
    #pragma unroll
    for (int e = 0; e < 2; ++e) {
        int li = e * 512 + tid;
        int R  = li >> 3;
        int xx = ((li & 7) << 4) ^ ((R & 7) << 4);
        srcA[e] = xq + (size_t)(brow + ((R << 1) | (xx >> 6))) * K + (xx & 63);
    }
    // B region 12KB = 768 chunks: li = tid (all), li = 512 + tid (tid < 256).
    const int8_t* srcB[2];
    #pragma unroll
    for (int e = 0; e < 2; ++e) {
        int li = e * 512 + (e == 1 ? (tid & 255) : tid);
        int R  = li >> 3;
        int xx = ((li & 7) << 4) ^ ((R & 7) << 4);
        srcB[e] = w + (size_t)(bcol + ((R << 1) | (xx >> 6))) * K + (xx & 63);
    }

    // fragment LDS byte offsets (R2-verified formula+pattern); B region at +16KB
    int offA[4], offB[6];
    #pragma unroll
    for (int m = 0; m < 4; ++m) {
        int r  = wr * 64 + m * 16 + (lane & 15);
        int R  = r >> 1;
        int x  = (((r & 1) << 6) | (lane & 48)) ^ ((R & 7) << 4);
        offA[m] = R * 128 + x;
    }
    #pragma unroll
    for (int n = 0; n < 6; ++n) {
        int r  = wc * 96 + n * 16 + (lane & 15);
        int R  = r >> 1;
        int x  = (((r & 1) << 6) | (lane & 48)) ^ ((R & 7) << 4);
        offB[n] = 16384 + R * 128 + x;
    }

    i32x4 acc[4][6] = {};

#define STAGE(NB, TT) do { const size_t ko = (size_t)(TT) << 6;          \
        gload16(srcA[0] + ko, &lds[NB][        wv * 1024]);              \
        gload16(srcA[1] + ko, &lds[NB][ 8192 + wv * 1024]);              \
        gload16(srcB[0] + ko, &lds[NB][16384 + wv * 1024]);              \
        if (tid < 256) gload16(srcB[1] + ko, &lds[NB][24576 + wv * 1024]); } while (0)

#define RA(BUF, V, MM) V = *(const i32x4*)(&lds[BUF][offA[MM]])
#define RB(BUF, V, NN) V = *(const i32x4*)(&lds[BUF][offB[NN]])

// 12 MFMAs: A frags (X0..X3) x B frags (Y0,Y1,Y2), acc cols NB..NB+2
#define DOZEN(X0, X1, X2, X3, Y0, Y1, Y2, NB)                       \
    SP1();                                                          \
    acc[0][NB+0]=MFMAI8(X0,Y0,acc[0][NB+0]); acc[1][NB+0]=MFMAI8(X1,Y0,acc[1][NB+0]); \
    acc[2][NB+0]=MFMAI8(X2,Y0,acc[2][NB+0]); acc[3][NB+0]=MFMAI8(X3,Y0,acc[3][NB+0]); \
    acc[0][NB+1]=MFMAI8(X0,Y1,acc[0][NB+1]); acc[1][NB+1]=MFMAI8(X1,Y1,acc[1][NB+1]); \
    acc[2][NB+1]=MFMAI8(X2,Y1,acc[2][NB+1]); acc[3][NB+1]=MFMAI8(X3,Y1,acc[3][NB+1]); \
    acc[0][NB+2]=MFMAI8(X0,Y2,acc[0][NB+2]); acc[1][NB+2]=MFMAI8(X1,Y2,acc[1][NB+2]); \
    acc[2][NB+2]=MFMAI8(X2,Y2,acc[2][NB+2]); acc[3][NB+2]=MFMAI8(X3,Y2,acc[3][NB+2]); \
    SP0();

#define TILE(BUF, TT, DOSTAGE) do {                                           \
        i32x4 a0,a1,a2,a3,b0,b1,b2,b3,b4,b5;                                  \
        VMCNT0(); BARRIER(); SB();                                            \
        RA(BUF,a0,0); RA(BUF,a1,1); RB(BUF,b0,0); RB(BUF,b1,1); SB();         \
        RA(BUF,a2,2); RA(BUF,a3,3); RB(BUF,b2,2); SB();                       \
        RB(BUF,b3,3); RB(BUF,b4,4); RB(BUF,b5,5); SB();                       \
        if (DOSTAGE) { STAGE(BUF ^ 1, (TT) + 1); }                            \
        SB();                                                                 \
        DOZEN(a0,a1,a2,a3, b0,b1,b2, 0); SB();                                \
        DOZEN(a0,a1,a2,a3, b3,b4,b5, 3); SB();                                \
    } while (0)

    const int NT = K >> 6;               // 64 for K=4096 (even)
    STAGE(0, 0);
    for (int t = 0; t < NT - 2; t += 2) {
        TILE(0, t,     true);
        TILE(1, t + 1, true);
    }
    TILE(0, NT - 2, true);               // stages tile NT-1 into buf 1
    TILE(1, NT - 1, false);

    // epilogue: out = acc * sx[row] * scale[col] + bias[col]
    const int orow = brow + wr * 64;
    const int ocol = bcol + wc * 96;
    float sxv[4][4];
    #pragma unroll
    for (int m = 0; m < 4; ++m)
        #pragma unroll
        for (int j = 0; j < 4; ++j)
            sxv[m][j] = sx[orow + m * 16 + ((lane >> 4) << 2) + j];
    #pragma unroll
    for (int n = 0; n < 6; ++n) {
        const int col = ocol + n * 16 + (lane & 15);
        const float sc = scale[col];
        const float bi = bias[col];
        #pragma unroll
        for (int m = 0; m < 4; ++m) {
            const int rb = orow + m * 16 + ((lane >> 4) << 2);
            #pragma unroll
            for (int j = 0; j < 4; ++j)
                out[(size_t)(rb + j) * N + col] = (float)acc[m][n][j] * sxv[m][j] * sc + bi;
        }
    }
}

extern "C" void kernel_launch(void* const* d_in, const int* in_sizes, int n_in,
                              void* d_out, int out_size, void* d_ws, size_t ws_size,
                              hipStream_t stream) {
    const float* x     = (const float*)d_in[0];
    const int*   w32   = (const int*)d_in[1];     // int8 weight arrives as int32 (harness ABI)
    const float* scale = (const float*)d_in[2];
    const float* bias  = (const float*)d_in[3];
    float* out = (float*)d_out;

    const int N = in_sizes[2];           // 6144
    const int K = in_sizes[1] / N;       // 4096
    const int M = in_sizes[0] / K;       // 4096

    // ws layout: xq [M*K int8] | wq [N*K int8] | sx [M f32]
    int8_t* xqbuf = (int8_t*)d_ws;
    int8_t* wqbuf = (int8_t*)d_ws + (size_t)M * K;
    float*  sxbuf = (float*)((uint8_t*)d_ws + (size_t)M * K + (size_t)N * K);

    if (K == 4096)
        quant4096<<<M, 256, 0, stream>>>(x, xqbuf, sxbuf);
    else
        quant_any<<<M, 256, 0, stream>>>(x, xqbuf, sxbuf, K);

    pack_w<<<2048, 256, 0, stream>>>(w32, wqbuf, (long long)N * K / 4);

    const int nwg = (M / 256) * (N / 192);   // 16*32 = 512
    gemm_i8<<<nwg, 512, 0, stream>>>(xqbuf, wqbuf, sxbuf, scale, bias, out, M, N, K);
}

// Round 21
// 141.102 us; speedup vs baseline: 1.0846x; 1.0846x over previous
//
#include <hip/hip_runtime.h>
#include <stdint.h>
#include <stddef.h>

typedef __attribute__((ext_vector_type(4))) int i32x4;

#define AS1q __attribute__((address_space(1)))
#define AS3q __attribute__((address_space(3)))

__device__ __forceinline__ void gload16(const void* g, void* l) {
    __builtin_amdgcn_global_load_lds((const AS1q uint32_t*)g, (AS3q uint32_t*)l, 16, 0, 0);
}

#define VMCNT0()  asm volatile("s_waitcnt vmcnt(0)" ::: "memory")
#define BARRIER() asm volatile("s_barrier" ::: "memory")
#define SB()      __builtin_amdgcn_sched_barrier(0)
#define SP1()     __builtin_amdgcn_s_setprio(1)
#define SP0()     __builtin_amdgcn_s_setprio(0)
#define MFMAI8(a, b, c) __builtin_amdgcn_mfma_i32_16x16x64_i8(a, b, c, 0, 0, 0)

#define EPSQ 1e-8f

// ---------------- Quant: one block per token (K == 4096 fast path) ----------------
__global__ __launch_bounds__(256) void quant4096(
    const float* __restrict__ x, int8_t* __restrict__ xq, float* __restrict__ sx)
{
    constexpr int K = 4096;
    const int t = blockIdx.x;
    const int tid = threadIdx.x;
    const float4* row4 = (const float4*)(x + (size_t)t * K);
    float4 v0 = row4[0 * 256 + tid];
    float4 v1 = row4[1 * 256 + tid];
    float4 v2 = row4[2 * 256 + tid];
    float4 v3 = row4[3 * 256 + tid];
    auto mx4 = [](float4 a) {
        return fmaxf(fmaxf(fabsf(a.x), fabsf(a.y)), fmaxf(fabsf(a.z), fabsf(a.w)));
    };
    float am = fmaxf(fmaxf(mx4(v0), mx4(v1)), fmaxf(mx4(v2), mx4(v3)));
    #pragma unroll
    for (int off = 32; off > 0; off >>= 1)
        am = fmaxf(am, __shfl_xor(am, off, 64));
    __shared__ float wmax[4];
    if ((tid & 63) == 0) wmax[tid >> 6] = am;
    __syncthreads();
    float r = fmaxf(fmaxf(wmax[0], wmax[1]), fmaxf(wmax[2], wmax[3]));
    const float s = fmaxf(r, EPSQ) / 127.0f;   // true fdiv: match reference
    if (tid == 0) sx[t] = s;
    int* qrow = (int*)(xq + (size_t)t * K);
    auto pack = [&](float4 a) {
        int q0 = (int)fminf(fmaxf(rintf(a.x / s), -128.f), 127.f);
        int q1 = (int)fminf(fmaxf(rintf(a.y / s), -128.f), 127.f);
        int q2 = (int)fminf(fmaxf(rintf(a.z / s), -128.f), 127.f);
        int q3 = (int)fminf(fmaxf(rintf(a.w / s), -128.f), 127.f);
        return (q0 & 255) | ((q1 & 255) << 8) | ((q2 & 255) << 16) | ((q3 & 255) << 24);
    };
    qrow[0 * 256 + tid] = pack(v0);
    qrow[1 * 256 + tid] = pack(v1);
    qrow[2 * 256 + tid] = pack(v2);
    qrow[3 * 256 + tid] = pack(v3);
}

// generic fallback (any K multiple of 4)
__global__ __launch_bounds__(256) void quant_any(
    const float* __restrict__ x, int8_t* __restrict__ xq, float* __restrict__ sx, int K)
{
    const int t = blockIdx.x;
    const int tid = threadIdx.x;
    const float* row = x + (size_t)t * K;
    float am = 0.f;
    for (int i = tid; i < K; i += 256) am = fmaxf(am, fabsf(row[i]));
    #pragma unroll
    for (int off = 32; off > 0; off >>= 1)
        am = fmaxf(am, __shfl_xor(am, off, 64));
    __shared__ float wmax[4];
    if ((tid & 63) == 0) wmax[tid >> 6] = am;
    __syncthreads();
    float r = fmaxf(fmaxf(wmax[0], wmax[1]), fmaxf(wmax[2], wmax[3]));
    const float s = fmaxf(r, EPSQ) / 127.0f;
    if (tid == 0) sx[t] = s;
    int8_t* qrow = xq + (size_t)t * K;
    for (int i = tid; i < K; i += 256) {
        float q = fminf(fmaxf(rintf(row[i] / s), -128.f), 127.f);
        qrow[i] = (int8_t)(int)q;
    }
}

// ---------------- Pack: weight arrives as int32 (harness ABI), repack to int8 ----------------
__global__ __launch_bounds__(256) void pack_w(
    const int* __restrict__ w32, int8_t* __restrict__ w8, long long n4)
{
    const long long stride = (long long)gridDim.x * 256;
    for (long long i = (long long)blockIdx.x * 256 + threadIdx.x; i < n4; i += stride) {
        int4 v = ((const int4*)w32)[i];
        ((int*)w8)[i] = (v.x & 255) | ((v.y & 255) << 8) | ((v.z & 255) << 16) | ((v.w & 255) << 24);
    }
}

// ---------------- int8 GEMM: R12 schedule, 16x16x64, 4Mx2N wave grid (BEST) ----------------
// Final configuration after 20 measured rounds. BM=256, BN=192, BK=128.
// 512 thr, 8 waves (4M x 2N), wave tile 64x96 = 4x6 frags of 16x16x64
// -> 48 MFMA + 20 ds_read_b128 per wave per tile.
// Measured: gemm 108.3-110us, MfmaUtil 42%, SQ_LDS_BANK_CONFLICT 0, VGPR 112.
// Schedule (best of 16 structures): straight-line sched_barrier(0)-walled
// read/MFMA group interleave; ONE vmcnt(0)+barrier per tile — stage issued a
// full ~4100cyc tile earlier so the drain is ~free AND all gload_lds LDS
// writes landed before the read burst (counted-vmcnt variants: -22%/-35%;
// BK=64 2-blocks/CU: -12%; 8-phase: -24%; 32x32 MFMA: bank conflicts).
// LDS: 2 bufs x 56KB = 112KB -> 1 block/CU, 2 waves/SIMD.
// Swizzle: R2-counter-verified two-64B-logical-rows-per-128B-phys-row XOR
// x^=(R&7)<<4; linear gload_lds dest + inverse-swizzled per-lane global src.
// Grid (M/256)*(N/192) = 512 = exactly 2 rounds/CU, zero tail waste.
__global__ __launch_bounds__(512, 2) void gemm_i8(
    const int8_t* __restrict__ xq, const int8_t* __restrict__ w,
    const float* __restrict__ sx, const float* __restrict__ scale,
    const float* __restrict__ bias, float* __restrict__ out,
    int M, int N, int K)
{
    __shared__ __align__(16) uint8_t lds[2][57344];   // [buf][A 32KB | B 24KB]
    const int tid  = threadIdx.x;
    const int lane = tid & 63;
    const int wv   = tid >> 6;
    const int wr   = wv >> 1, wc = wv & 1;           // 4M x 2N

    // bijective XCD swizzle (m204); nwg=512 -> %8==0
    const int nwg = gridDim.x;
    const int q8 = nwg >> 3, r8 = nwg & 7;
    const int xcd = blockIdx.x & 7, idx8 = blockIdx.x >> 3;
    const int wg = (xcd < r8 ? xcd * (q8 + 1) : r8 * (q8 + 1) + (xcd - r8) * q8) + idx8;

    const int NBM = M >> 8;
    const int bm = wg % NBM;
    const int bn = wg / NBM;             // col-panel-major: B panel (768KB) L2-resident
    const int brow = bm << 8, bcol = bn * 192;

    // staging sources (inverse-swizzled; R2-verified formula)
    const int8_t* srcA[4];
    #pragma unroll
    for (int e = 0; e < 4; ++e) {
        int half = e >> 1;
        int li = (e & 1) * 512 + tid;
        int R  = li >> 3;
        int xx = ((li & 7) << 4) ^ ((R & 7) << 4);
        srcA[e] = xq + (size_t)(brow + ((R << 1) | (xx >> 6))) * K + half * 64 + (xx & 63);
    }
    const int8_t* srcB[3];
    #pragma unroll
    for (int e = 0; e < 3; ++e) {
        int li = e * 512 + tid;
        int halfB = (li >= 768) ? 1 : 0;
        int lw = li - halfB * 768;
        int R  = lw >> 3;
        int xx = ((li & 7) << 4) ^ ((R & 7) << 4);
        srcB[e] = w + (size_t)(bcol + ((R << 1) | (xx >> 6))) * K + halfB * 64 + (xx & 63);
    }

    // fragment LDS byte offsets within a half-region (R2-verified formula+pattern)
    int offA[4], offB[6];
    #pragma unroll
    for (int m = 0; m < 4; ++m) {
        int r  = wr * 64 + m * 16 + (lane & 15);
        int R  = r >> 1;
        int x  = (((r & 1) << 6) | (lane & 48)) ^ ((R & 7) << 4);
        offA[m] = R * 128 + x;
    }
    #pragma unroll
    for (int n = 0; n < 6; ++n) {
        int r  = wc * 96 + n * 16 + (lane & 15);
        int R  = r >> 1;
        int x  = (((r & 1) << 6) | (lane & 48)) ^ ((R & 7) << 4);
        offB[n] = R * 128 + x;
    }

    i32x4 acc[4][6] = {};

#define STAGE(NB, TT) do { const size_t ko = (size_t)(TT) << 7;      \
        gload16(srcA[0] + ko, &lds[NB][        wv * 1024]);          \
        gload16(srcA[1] + ko, &lds[NB][ 8192 + wv * 1024]);          \
        gload16(srcA[2] + ko, &lds[NB][16384 + wv * 1024]);          \
        gload16(srcA[3] + ko, &lds[NB][24576 + wv * 1024]);          \
        gload16(srcB[0] + ko, &lds[NB][32768 + wv * 1024]);          \
        gload16(srcB[1] + ko, &lds[NB][40960 + wv * 1024]);          \
        gload16(srcB[2] + ko, &lds[NB][49152 + wv * 1024]); } while (0)

#define RA(BUF, HH, V, MM) V = *(const i32x4*)(&lds[BUF][(HH) * 16384 + offA[MM]])
#define RB(BUF, HH, V, NN) V = *(const i32x4*)(&lds[BUF][32768 + (HH) * 12288 + offB[NN]])

// 12 MFMAs: A frags (X0..X3) x B frags (Y0,Y1,Y2), acc cols NB..NB+2
#define DOZEN(X0, X1, X2, X3, Y0, Y1, Y2, NB)                       \
    SP1();                                                          \
    acc[0][NB+0]=MFMAI8(X0,Y0,acc[0][NB+0]); acc[1][NB+0]=MFMAI8(X1,Y0,acc[1][NB+0]); \
    acc[2][NB+0]=MFMAI8(X2,Y0,acc[2][NB+0]); acc[3][NB+0]=MFMAI8(X3,Y0,acc[3][NB+0]); \
    acc[0][NB+1]=MFMAI8(X0,Y1,acc[0][NB+1]); acc[1][NB+1]=MFMAI8(X1,Y1,acc[1][NB+1]); \
    acc[2][NB+1]=MFMAI8(X2,Y1,acc[2][NB+1]); acc[3][NB+1]=MFMAI8(X3,Y1,acc[3][NB+1]); \
    acc[0][NB+2]=MFMAI8(X0,Y2,acc[0][NB+2]); acc[1][NB+2]=MFMAI8(X1,Y2,acc[1][NB+2]); \
    acc[2][NB+2]=MFMAI8(X2,Y2,acc[2][NB+2]); acc[3][NB+2]=MFMAI8(X3,Y2,acc[3][NB+2]); \
    SP0();

#define TILE(BUF, TT, DOSTAGE) do {                                           \
        i32x4 a0,a1,a2,a3,b0,b1,b2,b3,b4,b5;                                  \
        i32x4 c0,c1,c2,c3,d0,d1,d2,d3,d4,d5;                                  \
        VMCNT0(); BARRIER(); SB();                                            \
        RA(BUF,0,a0,0); RA(BUF,0,a1,1); RB(BUF,0,b0,0); RB(BUF,0,b1,1); SB(); \
        RA(BUF,0,a2,2); RA(BUF,0,a3,3); RB(BUF,0,b2,2); SB();                 \
        RB(BUF,0,b3,3); RB(BUF,0,b4,4); RB(BUF,0,b5,5); SB();                 \
        if (DOSTAGE) { STAGE(BUF ^ 1, (TT) + 1); }                            \
        SB();                                                                 \
        DOZEN(a0,a1,a2,a3, b0,b1,b2, 0); SB();                                \
        RA(BUF,1,c0,0); RA(BUF,1,c1,1); RB(BUF,1,d0,0); RB(BUF,1,d1,1); SB(); \
        RA(BUF,1,c2,2); RA(BUF,1,c3,3); RB(BUF,1,d2,2); SB();                 \
        DOZEN(a0,a1,a2,a3, b3,b4,b5, 3); SB();                                \
        RB(BUF,1,d3,3); RB(BUF,1,d4,4); RB(BUF,1,d5,5); SB();                 \
        DOZEN(c0,c1,c2,c3, d0,d1,d2, 0); SB();                                \
        DOZEN(c0,c1,c2,c3, d3,d4,d5, 3); SB();                                \
    } while (0)

    const int NT = K >> 7;               // 32 for K=4096 (even)
    STAGE(0, 0);
    for (int t = 0; t < NT - 2; t += 2) {
        TILE(0, t,     true);
        TILE(1, t + 1, true);
    }
    TILE(0, NT - 2, true);               // stages tile NT-1 into buf 1
    TILE(1, NT - 1, false);

    // epilogue: out = acc * sx[row] * scale[col] + bias[col]
    const int orow = brow + wr * 64;
    const int ocol = bcol + wc * 96;
    float sxv[4][4];
    #pragma unroll
    for (int m = 0; m < 4; ++m)
        #pragma unroll
        for (int j = 0; j < 4; ++j)
            sxv[m][j] = sx[orow + m * 16 + ((lane >> 4) << 2) + j];
    #pragma unroll
    for (int n = 0; n < 6; ++n) {
        const int col = ocol + n * 16 + (lane & 15);
        const float sc = scale[col];
        const float bi = bias[col];
        #pragma unroll
        for (int m = 0; m < 4; ++m) {
            const int rb = orow + m * 16 + ((lane >> 4) << 2);
            #pragma unroll
            for (int j = 0; j < 4; ++j)
                out[(size_t)(rb + j) * N + col] = (float)acc[m][n][j] * sxv[m][j] * sc + bi;
        }
    }
}

extern "C" void kernel_launch(void* const* d_in, const int* in_sizes, int n_in,
                              void* d_out, int out_size, void* d_ws, size_t ws_size,
                              hipStream_t stream) {
    const float* x     = (const float*)d_in[0];
    const int*   w32   = (const int*)d_in[1];     // int8 weight arrives as int32 (harness ABI)
    const float* scale = (const float*)d_in[2];
    const float* bias  = (const float*)d_in[3];
    float* out = (float*)d_out;

    const int N = in_sizes[2];           // 6144
    const int K = in_sizes[1] / N;       // 4096
    const int M = in_sizes[0] / K;       // 4096

    // ws layout: xq [M*K int8] | wq [N*K int8] | sx [M f32]
    int8_t* xqbuf = (int8_t*)d_ws;
    int8_t* wqbuf = (int8_t*)d_ws + (size_t)M * K;
    float*  sxbuf = (float*)((uint8_t*)d_ws + (size_t)M * K + (size_t)N * K);

    if (K == 4096)
        quant4096<<<M, 256, 0, stream>>>(x, xqbuf, sxbuf);
    else
        quant_any<<<M, 256, 0, stream>>>(x, xqbuf, sxbuf, K);

    pack_w<<<2048, 256, 0, stream>>>(w32, wqbuf, (long long)N * K / 4);

    const int nwg = (M / 256) * (N / 192);   // 16*32 = 512
    gemm_i8<<<nwg, 512, 0, stream>>>(xqbuf, wqbuf, sxbuf, scale, bias, out, M, N, K);
}

// Round 22
// 140.827 us; speedup vs baseline: 1.0867x; 1.0019x over previous
//
#include <hip/hip_runtime.h>
#include <stdint.h>
#include <stddef.h>

typedef __attribute__((ext_vector_type(4))) int i32x4;

#define AS1q __attribute__((address_space(1)))
#define AS3q __attribute__((address_space(3)))

__device__ __forceinline__ void gload16(const void* g, void* l) {
    __builtin_amdgcn_global_load_lds((const AS1q uint32_t*)g, (AS3q uint32_t*)l, 16, 0, 0);
}

#define VMCNT0()  asm volatile("s_waitcnt vmcnt(0)" ::: "memory")
#define BARRIER() asm volatile("s_barrier" ::: "memory")
#define SB()      __builtin_amdgcn_sched_barrier(0)
// A/B vs R21: setprio removed. m190 measured setprio NEGATIVE (-1.5%) on
// barrier-locked GEMM structures (ours); its +21% case (m218b) requires the
// 8-phase role-split schedule, which measured worse here anyway (R9).
#define SP1()
#define SP0()
#define MFMAI8(a, b, c) __builtin_amdgcn_mfma_i32_16x16x64_i8(a, b, c, 0, 0, 0)

#define EPSQ 1e-8f

// ---------------- Quant: one block per token (K == 4096 fast path) ----------------
__global__ __launch_bounds__(256) void quant4096(
    const float* __restrict__ x, int8_t* __restrict__ xq, float* __restrict__ sx)
{
    constexpr int K = 4096;
    const int t = blockIdx.x;
    const int tid = threadIdx.x;
    const float4* row4 = (const float4*)(x + (size_t)t * K);
    float4 v0 = row4[0 * 256 + tid];
    float4 v1 = row4[1 * 256 + tid];
    float4 v2 = row4[2 * 256 + tid];
    float4 v3 = row4[3 * 256 + tid];
    auto mx4 = [](float4 a) {
        return fmaxf(fmaxf(fabsf(a.x), fabsf(a.y)), fmaxf(fabsf(a.z), fabsf(a.w)));
    };
    float am = fmaxf(fmaxf(mx4(v0), mx4(v1)), fmaxf(mx4(v2), mx4(v3)));
    #pragma unroll
    for (int off = 32; off > 0; off >>= 1)
        am = fmaxf(am, __shfl_xor(am, off, 64));
    __shared__ float wmax[4];
    if ((tid & 63) == 0) wmax[tid >> 6] = am;
    __syncthreads();
    float r = fmaxf(fmaxf(wmax[0], wmax[1]), fmaxf(wmax[2], wmax[3]));
    const float s = fmaxf(r, EPSQ) / 127.0f;   // true fdiv: match reference
    if (tid == 0) sx[t] = s;
    int* qrow = (int*)(xq + (size_t)t * K);
    auto pack = [&](float4 a) {
        int q0 = (int)fminf(fmaxf(rintf(a.x / s), -128.f), 127.f);
        int q1 = (int)fminf(fmaxf(rintf(a.y / s), -128.f), 127.f);
        int q2 = (int)fminf(fmaxf(rintf(a.z / s), -128.f), 127.f);
        int q3 = (int)fminf(fmaxf(rintf(a.w / s), -128.f), 127.f);
        return (q0 & 255) | ((q1 & 255) << 8) | ((q2 & 255) << 16) | ((q3 & 255) << 24);
    };
    qrow[0 * 256 + tid] = pack(v0);
    qrow[1 * 256 + tid] = pack(v1);
    qrow[2 * 256 + tid] = pack(v2);
    qrow[3 * 256 + tid] = pack(v3);
}

// generic fallback (any K multiple of 4)
__global__ __launch_bounds__(256) void quant_any(
    const float* __restrict__ x, int8_t* __restrict__ xq, float* __restrict__ sx, int K)
{
    const int t = blockIdx.x;
    const int tid = threadIdx.x;
    const float* row = x + (size_t)t * K;
    float am = 0.f;
    for (int i = tid; i < K; i += 256) am = fmaxf(am, fabsf(row[i]));
    #pragma unroll
    for (int off = 32; off > 0; off >>= 1)
        am = fmaxf(am, __shfl_xor(am, off, 64));
    __shared__ float wmax[4];
    if ((tid & 63) == 0) wmax[tid >> 6] = am;
    __syncthreads();
    float r = fmaxf(fmaxf(wmax[0], wmax[1]), fmaxf(wmax[2], wmax[3]));
    const float s = fmaxf(r, EPSQ) / 127.0f;
    if (tid == 0) sx[t] = s;
    int8_t* qrow = xq + (size_t)t * K;
    for (int i = tid; i < K; i += 256) {
        float q = fminf(fmaxf(rintf(row[i] / s), -128.f), 127.f);
        qrow[i] = (int8_t)(int)q;
    }
}

// ---------------- Pack: weight arrives as int32 (harness ABI), repack to int8 ----------------
__global__ __launch_bounds__(256) void pack_w(
    const int* __restrict__ w32, int8_t* __restrict__ w8, long long n4)
{
    const long long stride = (long long)gridDim.x * 256;
    for (long long i = (long long)blockIdx.x * 256 + threadIdx.x; i < n4; i += stride) {
        int4 v = ((const int4*)w32)[i];
        ((int*)w8)[i] = (v.x & 255) | ((v.y & 255) << 8) | ((v.z & 255) << 16) | ((v.w & 255) << 24);
    }
}

// ---------------- int8 GEMM: R12 schedule, 16x16x64, 4Mx2N wave grid ----------------
// Best-measured configuration (R19/R21: gemm 108.3-110us, MfmaUtil 42%,
// conflicts 0, VGPR 112); this round's single change is setprio removal (A/B).
// BM=256, BN=192, BK=128. 512 thr, 8 waves (4M x 2N), wave tile 64x96 = 4x6
// frags of 16x16x64 -> 48 MFMA + 20 ds_read_b128 per wave per tile.
// Schedule (best of 16 structures): straight-line sched_barrier(0)-walled
// read/MFMA group interleave; ONE vmcnt(0)+barrier per tile — stage issued a
// full ~4100cyc tile earlier so the drain is ~free AND all gload_lds LDS
// writes landed before the read burst (counted-vmcnt: -22%/-35%; BK=64
// 2-blocks/CU: -12%; 8-phase: -24%; 32x32 MFMA: bank conflicts).
// LDS: 2 bufs x 56KB = 112KB -> 1 block/CU, 2 waves/SIMD.
// Swizzle: R2-counter-verified two-64B-logical-rows-per-128B-phys-row XOR
// x^=(R&7)<<4; linear gload_lds dest + inverse-swizzled per-lane global src.
// Grid (M/256)*(N/192) = 512 = exactly 2 rounds/CU, zero tail waste.
__global__ __launch_bounds__(512, 2) void gemm_i8(
    const int8_t* __restrict__ xq, const int8_t* __restrict__ w,
    const float* __restrict__ sx, const float* __restrict__ scale,
    const float* __restrict__ bias, float* __restrict__ out,
    int M, int N, int K)
{
    __shared__ __align__(16) uint8_t lds[2][57344];   // [buf][A 32KB | B 24KB]
    const int tid  = threadIdx.x;
    const int lane = tid & 63;
    const int wv   = tid >> 6;
    const int wr   = wv >> 1, wc = wv & 1;           // 4M x 2N

    // bijective XCD swizzle (m204); nwg=512 -> %8==0
    const int nwg = gridDim.x;
    const int q8 = nwg >> 3, r8 = nwg & 7;
    const int xcd = blockIdx.x & 7, idx8 = blockIdx.x >> 3;
    const int wg = (xcd < r8 ? xcd * (q8 + 1) : r8 * (q8 + 1) + (xcd - r8) * q8) + idx8;

    const int NBM = M >> 8;
    const int bm = wg % NBM;
    const int bn = wg / NBM;             // col-panel-major: B panel (768KB) L2-resident
    const int brow = bm << 8, bcol = bn * 192;

    // staging sources (inverse-swizzled; R2-verified formula)
    const int8_t* srcA[4];
    #pragma unroll
    for (int e = 0; e < 4; ++e) {
        int half = e >> 1;
        int li = (e & 1) * 512 + tid;
        int R  = li >> 3;
        int xx = ((li & 7) << 4) ^ ((R & 7) << 4);
        srcA[e] = xq + (size_t)(brow + ((R << 1) | (xx >> 6))) * K + half * 64 + (xx & 63);
    }
    const int8_t* srcB[3];
    #pragma unroll
    for (int e = 0; e < 3; ++e) {
        int li = e * 512 + tid;
        int halfB = (li >= 768) ? 1 : 0;
        int lw = li - halfB * 768;
        int R  = lw >> 3;
        int xx = ((li & 7) << 4) ^ ((R & 7) << 4);
        srcB[e] = w + (size_t)(bcol + ((R << 1) | (xx >> 6))) * K + halfB * 64 + (xx & 63);
    }

    // fragment LDS byte offsets within a half-region (R2-verified formula+pattern)
    int offA[4], offB[6];
    #pragma unroll
    for (int m = 0; m < 4; ++m) {
        int r  = wr * 64 + m * 16 + (lane & 15);
        int R  = r >> 1;
        int x  = (((r & 1) << 6) | (lane & 48)) ^ ((R & 7) << 4);
        offA[m] = R * 128 + x;
    }
    #pragma unroll
    for (int n = 0; n < 6; ++n) {
        int r  = wc * 96 + n * 16 + (lane & 15);
        int R  = r >> 1;
        int x  = (((r & 1) << 6) | (lane & 48)) ^ ((R & 7) << 4);
        offB[n] = R * 128 + x;
    }

    i32x4 acc[4][6] = {};

#define STAGE(NB, TT) do { const size_t ko = (size_t)(TT) << 7;      \
        gload16(srcA[0] + ko, &lds[NB][        wv * 1024]);          \
        gload16(srcA[1] + ko, &lds[NB][ 8192 + wv * 1024]);          \
        gload16(srcA[2] + ko, &lds[NB][16384 + wv * 1024]);          \
        gload16(srcA[3] + ko, &lds[NB][24576 + wv * 1024]);          \
        gload16(srcB[0] + ko, &lds[NB][32768 + wv * 1024]);          \
        gload16(srcB[1] + ko, &lds[NB][40960 + wv * 1024]);          \
        gload16(srcB[2] + ko, &lds[NB][49152 + wv * 1024]); } while (0)

#define RA(BUF, HH, V, MM) V = *(const i32x4*)(&lds[BUF][(HH) * 16384 + offA[MM]])
#define RB(BUF, HH, V, NN) V = *(const i32x4*)(&lds[BUF][32768 + (HH) * 12288 + offB[NN]])

// 12 MFMAs: A frags (X0..X3) x B frags (Y0,Y1,Y2), acc cols NB..NB+2
#define DOZEN(X0, X1, X2, X3, Y0, Y1, Y2, NB)                       \
    SP1();                                                          \
    acc[0][NB+0]=MFMAI8(X0,Y0,acc[0][NB+0]); acc[1][NB+0]=MFMAI8(X1,Y0,acc[1][NB+0]); \
    acc[2][NB+0]=MFMAI8(X2,Y0,acc[2][NB+0]); acc[3][NB+0]=MFMAI8(X3,Y0,acc[3][NB+0]); \
    acc[0][NB+1]=MFMAI8(X0,Y1,acc[0][NB+1]); acc[1][NB+1]=MFMAI8(X1,Y1,acc[1][NB+1]); \
    acc[2][NB+1]=MFMAI8(X2,Y1,acc[2][NB+1]); acc[3][NB+1]=MFMAI8(X3,Y1,acc[3][NB+1]); \
    acc[0][NB+2]=MFMAI8(X0,Y2,acc[0][NB+2]); acc[1][NB+2]=MFMAI8(X1,Y2,acc[1][NB+2]); \
    acc[2][NB+2]=MFMAI8(X2,Y2,acc[2][NB+2]); acc[3][NB+2]=MFMAI8(X3,Y2,acc[3][NB+2]); \
    SP0();

#define TILE(BUF, TT, DOSTAGE) do {                                           \
        i32x4 a0,a1,a2,a3,b0,b1,b2,b3,b4,b5;                                  \
        i32x4 c0,c1,c2,c3,d0,d1,d2,d3,d4,d5;                                  \
        VMCNT0(); BARRIER(); SB();                                            \
        RA(BUF,0,a0,0); RA(BUF,0,a1,1); RB(BUF,0,b0,0); RB(BUF,0,b1,1); SB(); \
        RA(BUF,0,a2,2); RA(BUF,0,a3,3); RB(BUF,0,b2,2); SB();                 \
        RB(BUF,0,b3,3); RB(BUF,0,b4,4); RB(BUF,0,b5,5); SB();                 \
        if (DOSTAGE) { STAGE(BUF ^ 1, (TT) + 1); }                            \
        SB();                                                                 \
        DOZEN(a0,a1,a2,a3, b0,b1,b2, 0); SB();                                \
        RA(BUF,1,c0,0); RA(BUF,1,c1,1); RB(BUF,1,d0,0); RB(BUF,1,d1,1); SB(); \
        RA(BUF,1,c2,2); RA(BUF,1,c3,3); RB(BUF,1,d2,2); SB();                 \
        DOZEN(a0,a1,a2,a3, b3,b4,b5, 3); SB();                                \
        RB(BUF,1,d3,3); RB(BUF,1,d4,4); RB(BUF,1,d5,5); SB();                 \
        DOZEN(c0,c1,c2,c3, d0,d1,d2, 0); SB();                                \
        DOZEN(c0,c1,c2,c3, d3,d4,d5, 3); SB();                                \
    } while (0)

    const int NT = K >> 7;               // 32 for K=4096 (even)
    STAGE(0, 0);
    for (int t = 0; t < NT - 2; t += 2) {
        TILE(0, t,     true);
        TILE(1, t + 1, true);
    }
    TILE(0, NT - 2, true);               // stages tile NT-1 into buf 1
    TILE(1, NT - 1, false);

    // epilogue: out = acc * sx[row] * scale[col] + bias[col]
    const int orow = brow + wr * 64;
    const int ocol = bcol + wc * 96;
    float sxv[4][4];
    #pragma unroll
    for (int m = 0; m < 4; ++m)
        #pragma unroll
        for (int j = 0; j < 4; ++j)
            sxv[m][j] = sx[orow + m * 16 + ((lane >> 4) << 2) + j];
    #pragma unroll
    for (int n = 0; n < 6; ++n) {
        const int col = ocol + n * 16 + (lane & 15);
        const float sc = scale[col];
        const float bi = bias[col];
        #pragma unroll
        for (int m = 0; m < 4; ++m) {
            const int rb = orow + m * 16 + ((lane >> 4) << 2);
            #pragma unroll
            for (int j = 0; j < 4; ++j)
                out[(size_t)(rb + j) * N + col] = (float)acc[m][n][j] * sxv[m][j] * sc + bi;
        }
    }
}

extern "C" void kernel_launch(void* const* d_in, const int* in_sizes, int n_in,
                              void* d_out, int out_size, void* d_ws, size_t ws_size,
                              hipStream_t stream) {
    const float* x     = (const float*)d_in[0];
    const int*   w32   = (const int*)d_in[1];     // int8 weight arrives as int32 (harness ABI)
    const float* scale = (const float*)d_in[2];
    const float* bias  = (const float*)d_in[3];
    float* out = (float*)d_out;

    const int N = in_sizes[2];           // 6144
    const int K = in_sizes[1] / N;       // 4096
    const int M = in_sizes[0] / K;       // 4096

    // ws layout: xq [M*K int8] | wq [N*K int8] | sx [M f32]
    int8_t* xqbuf = (int8_t*)d_ws;
    int8_t* wqbuf = (int8_t*)d_ws + (size_t)M * K;
    float*  sxbuf = (float*)((uint8_t*)d_ws + (size_t)M * K + (size_t)N * K);

    if (K == 4096)
        quant4096<<<M, 256, 0, stream>>>(x, xqbuf, sxbuf);
    else
        quant_any<<<M, 256, 0, stream>>>(x, xqbuf, sxbuf, K);

    pack_w<<<2048, 256, 0, stream>>>(w32, wqbuf, (long long)N * K / 4);

    const int nwg = (M / 256) * (N / 192);   // 16*32 = 512
    gemm_i8<<<nwg, 512, 0, stream>>>(xqbuf, wqbuf, sxbuf, scale, bias, out, M, N, K);
}

// Round 23
// 139.741 us; speedup vs baseline: 1.0952x; 1.0078x over previous
//
#include <hip/hip_runtime.h>
#include <stdint.h>
#include <stddef.h>

typedef __attribute__((ext_vector_type(4))) int i32x4;

#define AS1q __attribute__((address_space(1)))
#define AS3q __attribute__((address_space(3)))

__device__ __forceinline__ void gload16(const void* g, void* l) {
    __builtin_amdgcn_global_load_lds((const AS1q uint32_t*)g, (AS3q uint32_t*)l, 16, 0, 0);
}

#define VMCNT0()  asm volatile("s_waitcnt vmcnt(0)" ::: "memory")
#define BARRIER() asm volatile("s_barrier" ::: "memory")
#define SB()      __builtin_amdgcn_sched_barrier(0)
// setprio compiled out: R22 A/B measured neutral-to-positive removal on this
// barrier-locked structure (consistent with m190's negative sign for lockstep GEMM).
#define SP1()
#define SP0()
#define MFMAI8(a, b, c) __builtin_amdgcn_mfma_i32_16x16x64_i8(a, b, c, 0, 0, 0)

#define EPSQ 1e-8f

// ---------------- Quant: one block per token (K == 4096 fast path) ----------------
__global__ __launch_bounds__(256) void quant4096(
    const float* __restrict__ x, int8_t* __restrict__ xq, float* __restrict__ sx)
{
    constexpr int K = 4096;
    const int t = blockIdx.x;
    const int tid = threadIdx.x;
    const float4* row4 = (const float4*)(x + (size_t)t * K);
    float4 v0 = row4[0 * 256 + tid];
    float4 v1 = row4[1 * 256 + tid];
    float4 v2 = row4[2 * 256 + tid];
    float4 v3 = row4[3 * 256 + tid];
    auto mx4 = [](float4 a) {
        return fmaxf(fmaxf(fabsf(a.x), fabsf(a.y)), fmaxf(fabsf(a.z), fabsf(a.w)));
    };
    float am = fmaxf(fmaxf(mx4(v0), mx4(v1)), fmaxf(mx4(v2), mx4(v3)));
    #pragma unroll
    for (int off = 32; off > 0; off >>= 1)
        am = fmaxf(am, __shfl_xor(am, off, 64));
    __shared__ float wmax[4];
    if ((tid & 63) == 0) wmax[tid >> 6] = am;
    __syncthreads();
    float r = fmaxf(fmaxf(wmax[0], wmax[1]), fmaxf(wmax[2], wmax[3]));
    const float s = fmaxf(r, EPSQ) / 127.0f;   // true fdiv: match reference
    if (tid == 0) sx[t] = s;
    int* qrow = (int*)(xq + (size_t)t * K);
    auto pack = [&](float4 a) {
        int q0 = (int)fminf(fmaxf(rintf(a.x / s), -128.f), 127.f);
        int q1 = (int)fminf(fmaxf(rintf(a.y / s), -128.f), 127.f);
        int q2 = (int)fminf(fmaxf(rintf(a.z / s), -128.f), 127.f);
        int q3 = (int)fminf(fmaxf(rintf(a.w / s), -128.f), 127.f);
        return (q0 & 255) | ((q1 & 255) << 8) | ((q2 & 255) << 16) | ((q3 & 255) << 24);
    };
    qrow[0 * 256 + tid] = pack(v0);
    qrow[1 * 256 + tid] = pack(v1);
    qrow[2 * 256 + tid] = pack(v2);
    qrow[3 * 256 + tid] = pack(v3);
}

// generic fallback (any K multiple of 4)
__global__ __launch_bounds__(256) void quant_any(
    const float* __restrict__ x, int8_t* __restrict__ xq, float* __restrict__ sx, int K)
{
    const int t = blockIdx.x;
    const int tid = threadIdx.x;
    const float* row = x + (size_t)t * K;
    float am = 0.f;
    for (int i = tid; i < K; i += 256) am = fmaxf(am, fabsf(row[i]));
    #pragma unroll
    for (int off = 32; off > 0; off >>= 1)
        am = fmaxf(am, __shfl_xor(am, off, 64));
    __shared__ float wmax[4];
    if ((tid & 63) == 0) wmax[tid >> 6] = am;
    __syncthreads();
    float r = fmaxf(fmaxf(wmax[0], wmax[1]), fmaxf(wmax[2], wmax[3]));
    const float s = fmaxf(r, EPSQ) / 127.0f;
    if (tid == 0) sx[t] = s;
    int8_t* qrow = xq + (size_t)t * K;
    for (int i = tid; i < K; i += 256) {
        float q = fminf(fmaxf(rintf(row[i] / s), -128.f), 127.f);
        qrow[i] = (int8_t)(int)q;
    }
}

// ---------------- Pack: weight arrives as int32 (harness ABI), repack to int8 ----------------
__global__ __launch_bounds__(256) void pack_w(
    const int* __restrict__ w32, int8_t* __restrict__ w8, long long n4)
{
    const long long stride = (long long)gridDim.x * 256;
    for (long long i = (long long)blockIdx.x * 256 + threadIdx.x; i < n4; i += stride) {
        int4 v = ((const int4*)w32)[i];
        ((int*)w8)[i] = (v.x & 255) | ((v.y & 255) << 8) | ((v.z & 255) << 16) | ((v.w & 255) << 24);
    }
}

// ---------------- int8 GEMM: R12 schedule, 16x16x64, 4Mx2N wave grid (FINAL) ----------------
// Best-measured configuration after 22 rounds: gemm 107.8-108.5us (~1910 TOPS,
// 48% of the 3944 TOPS i8 ceiling), MfmaUtil 42%, SQ_LDS_BANK_CONFLICT 0,
// VGPR 112, total 140.8us.
// BM=256, BN=192, BK=128. 512 thr, 8 waves (4M x 2N), wave tile 64x96 = 4x6
// frags of 16x16x64 -> 48 MFMA + 20 ds_read_b128 per wave per tile.
// Schedule (best of 16 structures measured): straight-line sched_barrier(0)-
// walled read/MFMA group interleave; ONE vmcnt(0)+barrier per tile — stage
// issued a full ~4100cyc tile earlier so the drain is ~free AND all gload_lds
// LDS writes land before the read burst (counted-vmcnt: -22%/-35%; BK=64
// 2-blocks/CU: -12%; 8-phase: -24%; 32x32 MFMA: bank conflicts; setprio: <=0).
// LDS: 2 bufs x 56KB = 112KB -> 1 block/CU, 2 waves/SIMD.
// Swizzle: counter-verified two-64B-logical-rows-per-128B-phys-row XOR
// x^=(R&7)<<4; linear gload_lds dest + inverse-swizzled per-lane global src.
// Grid (M/256)*(N/192) = 512 = exactly 2 rounds/CU, zero tail waste.
__global__ __launch_bounds__(512, 2) void gemm_i8(
    const int8_t* __restrict__ xq, const int8_t* __restrict__ w,
    const float* __restrict__ sx, const float* __restrict__ scale,
    const float* __restrict__ bias, float* __restrict__ out,
    int M, int N, int K)
{
    __shared__ __align__(16) uint8_t lds[2][57344];   // [buf][A 32KB | B 24KB]
    const int tid  = threadIdx.x;
    const int lane = tid & 63;
    const int wv   = tid >> 6;
    const int wr   = wv >> 1, wc = wv & 1;           // 4M x 2N

    // bijective XCD swizzle (m204); nwg=512 -> %8==0
    const int nwg = gridDim.x;
    const int q8 = nwg >> 3, r8 = nwg & 7;
    const int xcd = blockIdx.x & 7, idx8 = blockIdx.x >> 3;
    const int wg = (xcd < r8 ? xcd * (q8 + 1) : r8 * (q8 + 1) + (xcd - r8) * q8) + idx8;

    const int NBM = M >> 8;
    const int bm = wg % NBM;
    const int bn = wg / NBM;             // col-panel-major: B panel (768KB) L2-resident
    const int brow = bm << 8, bcol = bn * 192;

    // staging sources (inverse-swizzled)
    const int8_t* srcA[4];
    #pragma unroll
    for (int e = 0; e < 4; ++e) {
        int half = e >> 1;
        int li = (e & 1) * 512 + tid;
        int R  = li >> 3;
        int xx = ((li & 7) << 4) ^ ((R & 7) << 4);
        srcA[e] = xq + (size_t)(brow + ((R << 1) | (xx >> 6))) * K + half * 64 + (xx & 63);
    }
    const int8_t* srcB[3];
    #pragma unroll
    for (int e = 0; e < 3; ++e) {
        int li = e * 512 + tid;
        int halfB = (li >= 768) ? 1 : 0;
        int lw = li - halfB * 768;
        int R  = lw >> 3;
        int xx = ((li & 7) << 4) ^ ((R & 7) << 4);
        srcB[e] = w + (size_t)(bcol + ((R << 1) | (xx >> 6))) * K + halfB * 64 + (xx & 63);
    }

    // fragment LDS byte offsets within a half-region
    int offA[4], offB[6];
    #pragma unroll
    for (int m = 0; m < 4; ++m) {
        int r  = wr * 64 + m * 16 + (lane & 15);
        int R  = r >> 1;
        int x  = (((r & 1) << 6) | (lane & 48)) ^ ((R & 7) << 4);
        offA[m] = R * 128 + x;
    }
    #pragma unroll
    for (int n = 0; n < 6; ++n) {
        int r  = wc * 96 + n * 16 + (lane & 15);
        int R  = r >> 1;
        int x  = (((r & 1) << 6) | (lane & 48)) ^ ((R & 7) << 4);
        offB[n] = R * 128 + x;
    }

    i32x4 acc[4][6] = {};

#define STAGE(NB, TT) do { const size_t ko = (size_t)(TT) << 7;      \
        gload16(srcA[0] + ko, &lds[NB][        wv * 1024]);          \
        gload16(srcA[1] + ko, &lds[NB][ 8192 + wv * 1024]);          \
        gload16(srcA[2] + ko, &lds[NB][16384 + wv * 1024]);          \
        gload16(srcA[3] + ko, &lds[NB][24576 + wv * 1024]);          \
        gload16(srcB[0] + ko, &lds[NB][32768 + wv * 1024]);          \
        gload16(srcB[1] + ko, &lds[NB][40960 + wv * 1024]);          \
        gload16(srcB[2] + ko, &lds[NB][49152 + wv * 1024]); } while (0)

#define RA(BUF, HH, V, MM) V = *(const i32x4*)(&lds[BUF][(HH) * 16384 + offA[MM]])
#define RB(BUF, HH, V, NN) V = *(const i32x4*)(&lds[BUF][32768 + (HH) * 12288 + offB[NN]])

// 12 MFMAs: A frags (X0..X3) x B frags (Y0,Y1,Y2), acc cols NB..NB+2
#define DOZEN(X0, X1, X2, X3, Y0, Y1, Y2, NB)                       \
    SP1();                                                          \
    acc[0][NB+0]=MFMAI8(X0,Y0,acc[0][NB+0]); acc[1][NB+0]=MFMAI8(X1,Y0,acc[1][NB+0]); \
    acc[2][NB+0]=MFMAI8(X2,Y0,acc[2][NB+0]); acc[3][NB+0]=MFMAI8(X3,Y0,acc[3][NB+0]); \
    acc[0][NB+1]=MFMAI8(X0,Y1,acc[0][NB+1]); acc[1][NB+1]=MFMAI8(X1,Y1,acc[1][NB+1]); \
    acc[2][NB+1]=MFMAI8(X2,Y1,acc[2][NB+1]); acc[3][NB+1]=MFMAI8(X3,Y1,acc[3][NB+1]); \
    acc[0][NB+2]=MFMAI8(X0,Y2,acc[0][NB+2]); acc[1][NB+2]=MFMAI8(X1,Y2,acc[1][NB+2]); \
    acc[2][NB+2]=MFMAI8(X2,Y2,acc[2][NB+2]); acc[3][NB+2]=MFMAI8(X3,Y2,acc[3][NB+2]); \
    SP0();

#define TILE(BUF, TT, DOSTAGE) do {                                           \
        i32x4 a0,a1,a2,a3,b0,b1,b2,b3,b4,b5;                                  \
        i32x4 c0,c1,c2,c3,d0,d1,d2,d3,d4,d5;                                  \
        VMCNT0(); BARRIER(); SB();                                            \
        RA(BUF,0,a0,0); RA(BUF,0,a1,1); RB(BUF,0,b0,0); RB(BUF,0,b1,1); SB(); \
        RA(BUF,0,a2,2); RA(BUF,0,a3,3); RB(BUF,0,b2,2); SB();                 \
        RB(BUF,0,b3,3); RB(BUF,0,b4,4); RB(BUF,0,b5,5); SB();                 \
        if (DOSTAGE) { STAGE(BUF ^ 1, (TT) + 1); }                            \
        SB();                                                                 \
        DOZEN(a0,a1,a2,a3, b0,b1,b2, 0); SB();                                \
        RA(BUF,1,c0,0); RA(BUF,1,c1,1); RB(BUF,1,d0,0); RB(BUF,1,d1,1); SB(); \
        RA(BUF,1,c2,2); RA(BUF,1,c3,3); RB(BUF,1,d2,2); SB();                 \
        DOZEN(a0,a1,a2,a3, b3,b4,b5, 3); SB();                                \
        RB(BUF,1,d3,3); RB(BUF,1,d4,4); RB(BUF,1,d5,5); SB();                 \
        DOZEN(c0,c1,c2,c3, d0,d1,d2, 0); SB();                                \
        DOZEN(c0,c1,c2,c3, d3,d4,d5, 3); SB();                                \
    } while (0)

    const int NT = K >> 7;               // 32 for K=4096 (even)
    STAGE(0, 0);
    for (int t = 0; t < NT - 2; t += 2) {
        TILE(0, t,     true);
        TILE(1, t + 1, true);
    }
    TILE(0, NT - 2, true);               // stages tile NT-1 into buf 1
    TILE(1, NT - 1, false);

    // epilogue: out = acc * sx[row] * scale[col] + bias[col]
    const int orow = brow + wr * 64;
    const int ocol = bcol + wc * 96;
    float sxv[4][4];
    #pragma unroll
    for (int m = 0; m < 4; ++m)
        #pragma unroll
        for (int j = 0; j < 4; ++j)
            sxv[m][j] = sx[orow + m * 16 + ((lane >> 4) << 2) + j];
    #pragma unroll
    for (int n = 0; n < 6; ++n) {
        const int col = ocol + n * 16 + (lane & 15);
        const float sc = scale[col];
        const float bi = bias[col];
        #pragma unroll
        for (int m = 0; m < 4; ++m) {
            const int rb = orow + m * 16 + ((lane >> 4) << 2);
            #pragma unroll
            for (int j = 0; j < 4; ++j)
                out[(size_t)(rb + j) * N + col] = (float)acc[m][n][j] * sxv[m][j] * sc + bi;
        }
    }
}

extern "C" void kernel_launch(void* const* d_in, const int* in_sizes, int n_in,
                              void* d_out, int out_size, void* d_ws, size_t ws_size,
                              hipStream_t stream) {
    const float* x     = (const float*)d_in[0];
    const int*   w32   = (const int*)d_in[1];     // int8 weight arrives as int32 (harness ABI)
    const float* scale = (const float*)d_in[2];
    const float* bias  = (const float*)d_in[3];
    float* out = (float*)d_out;

    const int N = in_sizes[2];           // 6144
    const int K = in_sizes[1] / N;       // 4096
    const int M = in_sizes[0] / K;       // 4096

    // ws layout: xq [M*K int8] | wq [N*K int8] | sx [M f32]
    int8_t* xqbuf = (int8_t*)d_ws;
    int8_t* wqbuf = (int8_t*)d_ws + (size_t)M * K;
    float*  sxbuf = (float*)((uint8_t*)d_ws + (size_t)M * K + (size_t)N * K);

    if (K == 4096)
        quant4096<<<M, 256, 0, stream>>>(x, xqbuf, sxbuf);
    else
        quant_any<<<M, 256, 0, stream>>>(x, xqbuf, sxbuf, K);

    pack_w<<<2048, 256, 0, stream>>>(w32, wqbuf, (long long)N * K / 4);

    const int nwg = (M / 256) * (N / 192);   // 16*32 = 512
    gemm_i8<<<nwg, 512, 0, stream>>>(xqbuf, wqbuf, sxbuf, scale, bias, out, M, N, K);
}